// Round 1
// baseline (695.527 us; speedup 1.0000x reference)
//
#include <hip/hip_runtime.h>
#include <math.h>

#define BB 16
#define CC 256
#define TT 8192
#define EE 32
#define NSPLIT 8

// workspace layout (float offsets)
#define OFF_M   0
#define OFF_VAR (OFF_M + BB*TT)            // 131072
#define OFF_DEN (OFF_VAR + BB*TT)          // 262144
#define OFF_Q   (OFF_DEN + 32)             // 262176
#define OFF_K   (OFF_Q + BB*CC*EE)         // 393248
#define OFF_GP  (OFF_K + BB*CC*EE)         // 524320
#define OFF_PCC (OFF_GP + NSPLIT*BB*CC*CC) // 8912928
// total ~9.97M floats (~38 MiB) of d_ws

// ---------------- stats: mean/var per (b,t), reduce over C ----------------
__global__ __launch_bounds__(256) void k_stats(const float* __restrict__ x,
                                               float* __restrict__ ws) {
  int bid = blockIdx.x;            // BB * (TT/256) = 512
  int b = bid >> 5;
  int t = ((bid & 31) << 8) | threadIdx.x;
  const float* xb = x + (size_t)b * CC * TT + t;
  float sum = 0.f, sq = 0.f;
#pragma unroll 4
  for (int c = 0; c < CC; ++c) {
    float v = xb[(size_t)c * TT];
    sum += v;
    sq = fmaf(v, v, sq);
  }
  float mean = sum * (1.0f / CC);
  float var = (sq - sum * mean) * (1.0f / (CC - 1));   // ddof=1
  ws[OFF_M + b * TT + t] = mean;
  ws[OFF_VAR + b * TT + t] = var;
}

// ---------------- denom[b] = sum_t var[b,t] ----------------
__global__ __launch_bounds__(256) void k_breduce(float* __restrict__ ws) {
  int b = blockIdx.x;              // BB
  const float* v = ws + OFF_VAR + (size_t)b * TT;
  float s = 0.f;
  for (int i = threadIdx.x; i < TT; i += 256) s += v[i];
#pragma unroll
  for (int off = 32; off; off >>= 1) s += __shfl_down(s, off, 64);
  __shared__ float red[4];
  int wid = threadIdx.x >> 6;
  if ((threadIdx.x & 63) == 0) red[wid] = s;
  __syncthreads();
  if (threadIdx.x == 0) ws[OFF_DEN + b] = red[0] + red[1] + red[2] + red[3];
}

// ---------------- centered Gram (= cov), K-split fp32 GEMM ----------------
#define KB 32
#define LDA 132
__global__ __launch_bounds__(256) void k_gram(const float* __restrict__ x,
                                              float* __restrict__ ws) {
  __shared__ float As[KB][LDA];
  __shared__ float Bs[KB][LDA];
  int blk = blockIdx.x;            // NSPLIT*4*BB = 512
  int s = blk & 7;
  int tij = (blk >> 3) & 3;
  int b = blk >> 5;
  int ti = (tij >> 1) * 128, tj = (tij & 1) * 128;
  int k0 = s * (TT / NSPLIT);

  const float* xb = x + (size_t)b * CC * TT;
  const float* mb = ws + OFF_M + (size_t)b * TT + k0;

  int tid = threadIdx.x;
  int lr = tid >> 3;               // 0..31
  int lk = (tid & 7) << 2;         // 0,4,..,28
  int tm = tid >> 4;               // 0..15
  int tn = tid & 15;               // 0..15

  float acc[8][8];
#pragma unroll
  for (int i = 0; i < 8; ++i)
#pragma unroll
    for (int j = 0; j < 8; ++j) acc[i][j] = 0.f;

  for (int kc = 0; kc < TT / NSPLIT; kc += KB) {
    float4 m4 = *(const float4*)(mb + kc + lk);
#pragma unroll
    for (int p = 0; p < 4; ++p) {
      int r = lr + (p << 5);
      float4 av = *(const float4*)(xb + (size_t)(ti + r) * TT + k0 + kc + lk);
      As[lk + 0][r] = av.x - m4.x;
      As[lk + 1][r] = av.y - m4.y;
      As[lk + 2][r] = av.z - m4.z;
      As[lk + 3][r] = av.w - m4.w;
      float4 bv = *(const float4*)(xb + (size_t)(tj + r) * TT + k0 + kc + lk);
      Bs[lk + 0][r] = bv.x - m4.x;
      Bs[lk + 1][r] = bv.y - m4.y;
      Bs[lk + 2][r] = bv.z - m4.z;
      Bs[lk + 3][r] = bv.w - m4.w;
    }
    __syncthreads();
#pragma unroll
    for (int k = 0; k < KB; ++k) {
      float4 a0 = *(const float4*)&As[k][tm * 4];
      float4 a1 = *(const float4*)&As[k][tm * 4 + 64];
      float4 b0 = *(const float4*)&Bs[k][tn * 4];
      float4 b1 = *(const float4*)&Bs[k][tn * 4 + 128 - 64];
      float av[8] = {a0.x, a0.y, a0.z, a0.w, a1.x, a1.y, a1.z, a1.w};
      float bv[8] = {b0.x, b0.y, b0.z, b0.w, b1.x, b1.y, b1.z, b1.w};
#pragma unroll
      for (int i = 0; i < 8; ++i)
#pragma unroll
        for (int j = 0; j < 8; ++j) acc[i][j] = fmaf(av[i], bv[j], acc[i][j]);
    }
    __syncthreads();
  }
  float* gp = ws + OFF_GP + ((size_t)s * BB + b) * CC * CC;
#pragma unroll
  for (int i = 0; i < 8; ++i) {
    int row = ti + tm * 4 + (i & 3) + (i >> 2) * 64;
    float* o = gp + (size_t)row * CC + tj;
    *(float4*)(o + tn * 4) = make_float4(acc[i][0], acc[i][1], acc[i][2], acc[i][3]);
    *(float4*)(o + tn * 4 + 64) = make_float4(acc[i][4], acc[i][5], acc[i][6], acc[i][7]);
  }
}

// ---------------- pcc = (sum_s GP) / denom ----------------
__global__ __launch_bounds__(256) void k_pccred(float* __restrict__ ws) {
  size_t idx = ((size_t)blockIdx.x * 256 + threadIdx.x) * 8;  // grid 512
  int b = (int)(idx >> 16);
  float inv = 1.0f / ws[OFF_DEN + b];
  float4 s0 = make_float4(0.f, 0.f, 0.f, 0.f);
  float4 s1 = s0;
#pragma unroll
  for (int s = 0; s < NSPLIT; ++s) {
    const float* g = ws + OFF_GP + (size_t)s * BB * CC * CC + idx;
    float4 a = *(const float4*)g;
    float4 c = *(const float4*)(g + 4);
    s0.x += a.x; s0.y += a.y; s0.z += a.z; s0.w += a.w;
    s1.x += c.x; s1.y += c.y; s1.z += c.z; s1.w += c.w;
  }
  float* o = ws + OFF_PCC + idx;
  *(float4*)o = make_float4(s0.x * inv, s0.y * inv, s0.z * inv, s0.w * inv);
  *(float4*)(o + 4) = make_float4(s1.x * inv, s1.y * inv, s1.z * inv, s1.w * inv);
}

// ---------------- q,k = pcc @ W^T + b ----------------
__global__ __launch_bounds__(256) void k_qk(const float* __restrict__ qw,
                                            const float* __restrict__ qb,
                                            const float* __restrict__ kw,
                                            const float* __restrict__ kb,
                                            float* __restrict__ ws) {
  __shared__ float wq[CC][EE];   // transposed weights: wq[d][e]
  __shared__ float wk[CC][EE];
  int blk = blockIdx.x;            // BB*4
  int b = blk >> 2;
  int c0 = (blk & 3) << 6;
  int tid = threadIdx.x;
  int e = tid & 31, d4 = tid >> 5; // d4: 0..7
#pragma unroll
  for (int p = 0; p < 8; ++p) {
    int dd = d4 * 4 + 32 * p;
    float4 qv = *(const float4*)(qw + (size_t)e * CC + dd);
    wq[dd + 0][e] = qv.x; wq[dd + 1][e] = qv.y; wq[dd + 2][e] = qv.z; wq[dd + 3][e] = qv.w;
    float4 kv = *(const float4*)(kw + (size_t)e * CC + dd);
    wk[dd + 0][e] = kv.x; wk[dd + 1][e] = kv.y; wk[dd + 2][e] = kv.z; wk[dd + 3][e] = kv.w;
  }
  __syncthreads();
  int r = tid >> 2;                // 0..63
  int eg = (tid & 3) << 3;         // 0,8,16,24
  float aq[8], ak[8];
#pragma unroll
  for (int j = 0; j < 8; ++j) { aq[j] = qb[eg + j]; ak[j] = kb[eg + j]; }
  const float* pr = ws + OFF_PCC + ((size_t)b * CC + c0 + r) * CC;
  for (int d = 0; d < CC; d += 4) {
    float4 p4 = *(const float4*)(pr + d);
    float pv[4] = {p4.x, p4.y, p4.z, p4.w};
#pragma unroll
    for (int u = 0; u < 4; ++u)
#pragma unroll
      for (int j = 0; j < 8; ++j) {
        aq[j] = fmaf(pv[u], wq[d + u][eg + j], aq[j]);
        ak[j] = fmaf(pv[u], wk[d + u][eg + j], ak[j]);
      }
  }
  float* qo = ws + OFF_Q + ((size_t)b * CC + c0 + r) * EE + eg;
  *(float4*)(qo + 0) = make_float4(aq[0], aq[1], aq[2], aq[3]);
  *(float4*)(qo + 4) = make_float4(aq[4], aq[5], aq[6], aq[7]);
  float* ko = ws + OFF_K + ((size_t)b * CC + c0 + r) * EE + eg;
  *(float4*)(ko + 0) = make_float4(ak[0], ak[1], ak[2], ak[3]);
  *(float4*)(ko + 4) = make_float4(ak[4], ak[5], ak[6], ak[7]);
}

// ---------------- scores + softmax -> attn (written into d_out tail) ----------------
__global__ __launch_bounds__(256) void k_attn(float* __restrict__ out,
                                              float* __restrict__ ws) {
  __shared__ float kl[CC][36];
  int blk = blockIdx.x;            // BB*4
  int b = blk >> 2;
  int c0 = (blk & 3) << 6;
  int tid = threadIdx.x;
  const float* kv = ws + OFF_K + (size_t)b * CC * EE;
#pragma unroll
  for (int p = 0; p < 8; ++p) {
    int flat = (tid + 256 * p) * 4;
    int d = flat >> 5, e = flat & 31;
    *(float4*)&kl[d][e] = *(const float4*)(kv + flat);
  }
  __syncthreads();
  int r = tid >> 2, dg = tid & 3;
  const float* q = ws + OFF_Q + ((size_t)b * CC + c0 + r) * EE;
  float qv[EE];
#pragma unroll
  for (int j = 0; j < EE; j += 4) {
    float4 t4 = *(const float4*)(q + j);
    qv[j] = t4.x; qv[j + 1] = t4.y; qv[j + 2] = t4.z; qv[j + 3] = t4.w;
  }
  float sc[64];
  float mx = -1e30f;
#pragma unroll
  for (int i = 0; i < 64; ++i) {
    int d = 4 * i + dg;
    float s = 0.f;
#pragma unroll
    for (int u = 0; u < EE; u += 4) {
      float4 k4 = *(const float4*)&kl[d][u];
      s = fmaf(qv[u], k4.x, s);
      s = fmaf(qv[u + 1], k4.y, s);
      s = fmaf(qv[u + 2], k4.z, s);
      s = fmaf(qv[u + 3], k4.w, s);
    }
    s *= 0.0625f;                  // 1/sqrt(256)
    sc[i] = s;
    mx = fmaxf(mx, s);
  }
  mx = fmaxf(mx, __shfl_xor(mx, 1));
  mx = fmaxf(mx, __shfl_xor(mx, 2));
  float sum = 0.f;
#pragma unroll
  for (int i = 0; i < 64; ++i) { sc[i] = __expf(sc[i] - mx); sum += sc[i]; }
  sum += __shfl_xor(sum, 1);
  sum += __shfl_xor(sum, 2);
  float inv = 1.0f / sum;
  float* ao = out + (size_t)BB * CC * TT + ((size_t)b * CC + c0 + r) * CC;
#pragma unroll
  for (int i = 0; i < 64; ++i) ao[4 * i + dg] = sc[i] * inv;
}

// ---------------- out = attn @ x ----------------
#define OKB 32
__global__ __launch_bounds__(256) void k_out(const float* __restrict__ x,
                                             const float* __restrict__ attn_src,
                                             float* __restrict__ out) {
  __shared__ float At[OKB][68];
  __shared__ float Xs[OKB][256];
  int blk = blockIdx.x;            // BB*4*32 = 2048
  int tt = blk & 31;
  int ct = (blk >> 5) & 3;
  int b = blk >> 7;
  int t0 = tt << 8;
  int c0 = ct << 6;
  const float* ab = attn_src + (size_t)b * CC * CC;
  const float* xb = x + (size_t)b * CC * TT;
  int tid = threadIdx.x;
  int tm = tid >> 5;               // 0..7
  int tn = tid & 31;               // 0..31

  float acc[8][8];
#pragma unroll
  for (int i = 0; i < 8; ++i)
#pragma unroll
    for (int j = 0; j < 8; ++j) acc[i][j] = 0.f;

  for (int kc = 0; kc < CC; kc += OKB) {
    {
      int lr = tid >> 3;           // 0..31
      int lk = (tid & 7) << 2;
#pragma unroll
      for (int p = 0; p < 2; ++p) {
        int r = lr + (p << 5);
        float4 av = *(const float4*)(ab + (size_t)(c0 + r) * CC + kc + lk);
        At[lk + 0][r] = av.x;
        At[lk + 1][r] = av.y;
        At[lk + 2][r] = av.z;
        At[lk + 3][r] = av.w;
      }
      int xk = tid >> 6;           // 0..3
      int xt = (tid & 63) << 2;
#pragma unroll
      for (int p = 0; p < 8; ++p) {
        int k = xk + (p << 2);
        *(float4*)&Xs[k][xt] = *(const float4*)(xb + (size_t)(kc + k) * TT + t0 + xt);
      }
    }
    __syncthreads();
#pragma unroll
    for (int k = 0; k < OKB; ++k) {
      float4 a0 = *(const float4*)&At[k][tm * 4];
      float4 a1 = *(const float4*)&At[k][tm * 4 + 32];
      float4 b0 = *(const float4*)&Xs[k][tn * 4];
      float4 b1 = *(const float4*)&Xs[k][tn * 4 + 128];
      float av[8] = {a0.x, a0.y, a0.z, a0.w, a1.x, a1.y, a1.z, a1.w};
      float bv[8] = {b0.x, b0.y, b0.z, b0.w, b1.x, b1.y, b1.z, b1.w};
#pragma unroll
      for (int i = 0; i < 8; ++i)
#pragma unroll
        for (int j = 0; j < 8; ++j) acc[i][j] = fmaf(av[i], bv[j], acc[i][j]);
    }
    __syncthreads();
  }
#pragma unroll
  for (int i = 0; i < 8; ++i) {
    int row = c0 + tm * 4 + (i & 3) + (i >> 2) * 32;
    float* o = out + ((size_t)b * CC + row) * TT + t0;
    *(float4*)(o + tn * 4) = make_float4(acc[i][0], acc[i][1], acc[i][2], acc[i][3]);
    *(float4*)(o + tn * 4 + 128) = make_float4(acc[i][4], acc[i][5], acc[i][6], acc[i][7]);
  }
}

extern "C" void kernel_launch(void* const* d_in, const int* in_sizes, int n_in,
                              void* d_out, int out_size, void* d_ws, size_t ws_size,
                              hipStream_t stream) {
  (void)in_sizes; (void)n_in; (void)out_size; (void)ws_size;
  const float* x = (const float*)d_in[0];
  const float* qw = (const float*)d_in[1];
  const float* qb = (const float*)d_in[2];
  const float* kw = (const float*)d_in[3];
  const float* kb = (const float*)d_in[4];
  float* out = (float*)d_out;
  float* ws = (float*)d_ws;

  hipLaunchKernelGGL(k_stats, dim3(BB * 32), dim3(256), 0, stream, x, ws);
  hipLaunchKernelGGL(k_breduce, dim3(BB), dim3(256), 0, stream, ws);
  hipLaunchKernelGGL(k_gram, dim3(NSPLIT * 4 * BB), dim3(256), 0, stream, x, ws);
  hipLaunchKernelGGL(k_pccred, dim3(512), dim3(256), 0, stream, ws);
  hipLaunchKernelGGL(k_qk, dim3(BB * 4), dim3(256), 0, stream, qw, qb, kw, kb, ws);
  hipLaunchKernelGGL(k_attn, dim3(BB * 4), dim3(256), 0, stream, out, ws);
  hipLaunchKernelGGL(k_out, dim3(BB * 4 * 32), dim3(256), 0, stream,
                     x, out + (size_t)BB * CC * TT, out);
}

// Round 5
// 465.353 us; speedup vs baseline: 1.4946x; 1.4946x over previous
//
#include <hip/hip_runtime.h>
#include <math.h>

#define BB 16
#define CC 256
#define TT 8192
#define EE 32
#define NSPLIT 8

// workspace layout (float offsets)
#define OFF_M   0
#define OFF_VAR (OFF_M + BB*TT)
#define OFF_DEN (OFF_VAR + BB*TT)
#define OFF_Q   (OFF_DEN + 32)
#define OFF_K   (OFF_Q + BB*CC*EE)
#define OFF_GP  (OFF_K + BB*CC*EE)
#define OFF_PCC (OFF_GP + NSPLIT*BB*CC*CC)
// total ~9.97M floats (~38 MiB) of d_ws

typedef __attribute__((ext_vector_type(8))) short bf16x8;
typedef __attribute__((ext_vector_type(4))) float f32x4;
typedef __attribute__((ext_vector_type(4))) unsigned int u32x4;

union FragU { u32x4 u; bf16x8 s; };

// pack the high 16 bits (truncated bf16) of two f32 into one u32: [f0hi | f1hi<<16]
__device__ __forceinline__ unsigned pack_hi2(float f0, float f1) {
  return __builtin_amdgcn_perm(__float_as_uint(f1), __float_as_uint(f0), 0x07060302u);
}

// split 8 f32 into hi (truncated bf16) and lo (bf16 of residual); hi+lo ~ 16-bit mantissa
__device__ __forceinline__ void split8(const float v[8], u32x4& hi, u32x4& lo) {
  float l[8];
#pragma unroll
  for (int i = 0; i < 8; ++i) {
    float h = __uint_as_float(__float_as_uint(v[i]) & 0xFFFF0000u);
    l[i] = v[i] - h;
  }
#pragma unroll
  for (int g = 0; g < 4; ++g) {
    hi[g] = pack_hi2(v[2 * g], v[2 * g + 1]);
    lo[g] = pack_hi2(l[2 * g], l[2 * g + 1]);
  }
}

// ---------------- stats: mean/var per (b,t), reduce over C ----------------
__global__ __launch_bounds__(256) void k_stats(const float* __restrict__ x,
                                               float* __restrict__ ws) {
  int bid = blockIdx.x;            // BB * (TT/256) = 512
  int b = bid >> 5;
  int t = ((bid & 31) << 8) | threadIdx.x;
  const float* xb = x + (size_t)b * CC * TT + t;
  float sum = 0.f, sq = 0.f;
#pragma unroll 4
  for (int c = 0; c < CC; ++c) {
    float v = xb[(size_t)c * TT];
    sum += v;
    sq = fmaf(v, v, sq);
  }
  float mean = sum * (1.0f / CC);
  float var = (sq - sum * mean) * (1.0f / (CC - 1));   // ddof=1
  ws[OFF_M + b * TT + t] = mean;
  ws[OFF_VAR + b * TT + t] = var;
}

// ---------------- denom[b] = sum_t var[b,t] ----------------
__global__ __launch_bounds__(256) void k_breduce(float* __restrict__ ws) {
  int b = blockIdx.x;              // BB
  const float* v = ws + OFF_VAR + (size_t)b * TT;
  float s = 0.f;
  for (int i = threadIdx.x; i < TT; i += 256) s += v[i];
#pragma unroll
  for (int off = 32; off; off >>= 1) s += __shfl_down(s, off, 64);
  __shared__ float red[4];
  int wid = threadIdx.x >> 6;
  if ((threadIdx.x & 63) == 0) red[wid] = s;
  __syncthreads();
  if (threadIdx.x == 0) ws[OFF_DEN + b] = red[0] + red[1] + red[2] + red[3];
}

// ---------------- centered Gram via bf16 hi/lo split MFMA ----------------
#define GK 64
__global__ __launch_bounds__(256, 2) void k_gram(const float* __restrict__ x,
                                                 float* __restrict__ ws) {
  // XOR-swizzled row-major tiles: elem idx = row*GK + (k ^ ((row&7)<<3))
  __shared__ __align__(16) unsigned short AH[128 * GK];
  __shared__ __align__(16) unsigned short AL[128 * GK];
  __shared__ __align__(16) unsigned short BH[128 * GK];
  __shared__ __align__(16) unsigned short BL[128 * GK];

  int blk = blockIdx.x;            // NSPLIT*4*BB = 512
  int s = blk & 7;
  int tij = (blk >> 3) & 3;
  int b = blk >> 5;
  int ti = (tij >> 1) * 128, tj = (tij & 1) * 128;
  int k0 = s * (TT / NSPLIT);

  const float* xb = x + (size_t)b * CC * TT;
  const float* mb = ws + OFF_M + (size_t)b * TT + k0;

  int tid = threadIdx.x;
  int lane = tid & 63;
  int w = tid >> 6;
  int wm = (w >> 1) * 64, wn = (w & 1) * 64;
  int fr = lane & 15;
  int fkb = (lane >> 4) * 8;
  int swz = (fr & 7) << 3;

  int sr = tid >> 1;               // staging row 0..127
  int sseg = (tid & 1) * 32;       // staging k offset
  int wbase = sr * GK;
  int wsz = (sr & 7) << 3;

  f32x4 acc[4][4];
  f32x4 z4 = {0.f, 0.f, 0.f, 0.f};
#pragma unroll
  for (int i = 0; i < 4; ++i)
#pragma unroll
    for (int j = 0; j < 4; ++j) acc[i][j] = z4;

  for (int kc = 0; kc < TT / NSPLIT; kc += GK) {
    const float* mr = mb + kc + sseg;
    const float* ar = xb + (size_t)(ti + sr) * TT + k0 + kc + sseg;
    const float* br = xb + (size_t)(tj + sr) * TT + k0 + kc + sseg;
#pragma unroll
    for (int g = 0; g < 4; ++g) {
      float m8[8], a8[8], b8[8];
      *(f32x4*)&m8[0] = *(const f32x4*)(mr + g * 8);
      *(f32x4*)&m8[4] = *(const f32x4*)(mr + g * 8 + 4);
      *(f32x4*)&a8[0] = *(const f32x4*)(ar + g * 8);
      *(f32x4*)&a8[4] = *(const f32x4*)(ar + g * 8 + 4);
      *(f32x4*)&b8[0] = *(const f32x4*)(br + g * 8);
      *(f32x4*)&b8[4] = *(const f32x4*)(br + g * 8 + 4);
#pragma unroll
      for (int i = 0; i < 8; ++i) { a8[i] -= m8[i]; b8[i] -= m8[i]; }
      u32x4 hi, lo;
      int idx = wbase + ((sseg + g * 8) ^ wsz);
      split8(a8, hi, lo);
      *(u32x4*)&AH[idx] = hi;
      *(u32x4*)&AL[idx] = lo;
      split8(b8, hi, lo);
      *(u32x4*)&BH[idx] = hi;
      *(u32x4*)&BL[idx] = lo;
    }
    __syncthreads();
#pragma unroll
    for (int ks = 0; ks < 2; ++ks) {
      int kb = (ks * 32 + fkb) ^ swz;
      FragU aH[4], aL[4], bH[4], bL[4];
#pragma unroll
      for (int m = 0; m < 4; ++m) {
        int ridx = (wm + m * 16 + fr) * GK + kb;
        aH[m].u = *(const u32x4*)&AH[ridx];
        aL[m].u = *(const u32x4*)&AL[ridx];
        int cidx = (wn + m * 16 + fr) * GK + kb;
        bH[m].u = *(const u32x4*)&BH[cidx];
        bL[m].u = *(const u32x4*)&BL[cidx];
      }
#pragma unroll
      for (int mi = 0; mi < 4; ++mi)
#pragma unroll
        for (int ni = 0; ni < 4; ++ni) {
          acc[mi][ni] = __builtin_amdgcn_mfma_f32_16x16x32_bf16(aH[mi].s, bH[ni].s, acc[mi][ni], 0, 0, 0);
          acc[mi][ni] = __builtin_amdgcn_mfma_f32_16x16x32_bf16(aH[mi].s, bL[ni].s, acc[mi][ni], 0, 0, 0);
          acc[mi][ni] = __builtin_amdgcn_mfma_f32_16x16x32_bf16(aL[mi].s, bH[ni].s, acc[mi][ni], 0, 0, 0);
        }
    }
    __syncthreads();
  }

  float* gp = ws + OFF_GP + ((size_t)s * BB + b) * CC * CC;
  int r4 = (lane >> 4) * 4;
#pragma unroll
  for (int mi = 0; mi < 4; ++mi) {
    int orow = ti + wm + mi * 16 + r4;
#pragma unroll
    for (int ni = 0; ni < 4; ++ni) {
      int ocol = tj + wn + ni * 16 + fr;
#pragma unroll
      for (int j = 0; j < 4; ++j)
        gp[(size_t)(orow + j) * CC + ocol] = acc[mi][ni][j];
    }
  }
}

// ---------------- pcc = (sum_s GP) / denom ----------------
__global__ __launch_bounds__(256) void k_pccred(float* __restrict__ ws) {
  size_t idx = ((size_t)blockIdx.x * 256 + threadIdx.x) * 8;  // grid 512
  int b = (int)(idx >> 16);
  float inv = 1.0f / ws[OFF_DEN + b];
  float4 s0 = make_float4(0.f, 0.f, 0.f, 0.f);
  float4 s1 = s0;
#pragma unroll
  for (int s = 0; s < NSPLIT; ++s) {
    const float* g = ws + OFF_GP + (size_t)s * BB * CC * CC + idx;
    float4 a = *(const float4*)g;
    float4 c = *(const float4*)(g + 4);
    s0.x += a.x; s0.y += a.y; s0.z += a.z; s0.w += a.w;
    s1.x += c.x; s1.y += c.y; s1.z += c.z; s1.w += c.w;
  }
  float* o = ws + OFF_PCC + idx;
  *(float4*)o = make_float4(s0.x * inv, s0.y * inv, s0.z * inv, s0.w * inv);
  *(float4*)(o + 4) = make_float4(s1.x * inv, s1.y * inv, s1.z * inv, s1.w * inv);
}

// ---------------- q,k = pcc @ W^T + b ----------------
__global__ __launch_bounds__(256) void k_qk(const float* __restrict__ qw,
                                            const float* __restrict__ qb,
                                            const float* __restrict__ kw,
                                            const float* __restrict__ kb,
                                            float* __restrict__ ws) {
  __shared__ float wq[CC][EE];
  __shared__ float wk[CC][EE];
  int blk = blockIdx.x;            // BB*4
  int b = blk >> 2;
  int c0 = (blk & 3) << 6;
  int tid = threadIdx.x;
  int e = tid & 31, d4 = tid >> 5;
#pragma unroll
  for (int p = 0; p < 8; ++p) {
    int dd = d4 * 4 + 32 * p;
    float4 qv = *(const float4*)(qw + (size_t)e * CC + dd);
    wq[dd + 0][e] = qv.x; wq[dd + 1][e] = qv.y; wq[dd + 2][e] = qv.z; wq[dd + 3][e] = qv.w;
    float4 kv = *(const float4*)(kw + (size_t)e * CC + dd);
    wk[dd + 0][e] = kv.x; wk[dd + 1][e] = kv.y; wk[dd + 2][e] = kv.z; wk[dd + 3][e] = kv.w;
  }
  __syncthreads();
  int r = tid >> 2;
  int eg = (tid & 3) << 3;
  float aq[8], ak[8];
#pragma unroll
  for (int j = 0; j < 8; ++j) { aq[j] = qb[eg + j]; ak[j] = kb[eg + j]; }
  const float* pr = ws + OFF_PCC + ((size_t)b * CC + c0 + r) * CC;
  for (int d = 0; d < CC; d += 4) {
    float4 p4 = *(const float4*)(pr + d);
    float pv[4] = {p4.x, p4.y, p4.z, p4.w};
#pragma unroll
    for (int u = 0; u < 4; ++u)
#pragma unroll
      for (int j = 0; j < 8; ++j) {
        aq[j] = fmaf(pv[u], wq[d + u][eg + j], aq[j]);
        ak[j] = fmaf(pv[u], wk[d + u][eg + j], ak[j]);
      }
  }
  float* qo = ws + OFF_Q + ((size_t)b * CC + c0 + r) * EE + eg;
  *(float4*)(qo + 0) = make_float4(aq[0], aq[1], aq[2], aq[3]);
  *(float4*)(qo + 4) = make_float4(aq[4], aq[5], aq[6], aq[7]);
  float* ko = ws + OFF_K + ((size_t)b * CC + c0 + r) * EE + eg;
  *(float4*)(ko + 0) = make_float4(ak[0], ak[1], ak[2], ak[3]);
  *(float4*)(ko + 4) = make_float4(ak[4], ak[5], ak[6], ak[7]);
}

// ---------------- scores + softmax -> attn (written into d_out tail) ----------------
__global__ __launch_bounds__(256) void k_attn(float* __restrict__ out,
                                              float* __restrict__ ws) {
  __shared__ float kl[CC][36];
  int blk = blockIdx.x;            // BB*4
  int b = blk >> 2;
  int c0 = (blk & 3) << 6;
  int tid = threadIdx.x;
  const float* kv = ws + OFF_K + (size_t)b * CC * EE;
#pragma unroll
  for (int p = 0; p < 8; ++p) {
    int flat = (tid + 256 * p) * 4;
    int d = flat >> 5, e = flat & 31;
    *(float4*)&kl[d][e] = *(const float4*)(kv + flat);
  }
  __syncthreads();
  int r = tid >> 2, dg = tid & 3;
  const float* q = ws + OFF_Q + ((size_t)b * CC + c0 + r) * EE;
  float qv[EE];
#pragma unroll
  for (int j = 0; j < EE; j += 4) {
    float4 t4 = *(const float4*)(q + j);
    qv[j] = t4.x; qv[j + 1] = t4.y; qv[j + 2] = t4.z; qv[j + 3] = t4.w;
  }
  float sc[64];
  float mx = -1e30f;
#pragma unroll
  for (int i = 0; i < 64; ++i) {
    int d = 4 * i + dg;
    float s = 0.f;
#pragma unroll
    for (int u = 0; u < EE; u += 4) {
      float4 k4 = *(const float4*)&kl[d][u];
      s = fmaf(qv[u], k4.x, s);
      s = fmaf(qv[u + 1], k4.y, s);
      s = fmaf(qv[u + 2], k4.z, s);
      s = fmaf(qv[u + 3], k4.w, s);
    }
    s *= 0.0625f;
    sc[i] = s;
    mx = fmaxf(mx, s);
  }
  mx = fmaxf(mx, __shfl_xor(mx, 1));
  mx = fmaxf(mx, __shfl_xor(mx, 2));
  float sum = 0.f;
#pragma unroll
  for (int i = 0; i < 64; ++i) { sc[i] = __expf(sc[i] - mx); sum += sc[i]; }
  sum += __shfl_xor(sum, 1);
  sum += __shfl_xor(sum, 2);
  float inv = 1.0f / sum;
  float* ao = out + (size_t)BB * CC * TT + ((size_t)b * CC + c0 + r) * CC;
#pragma unroll
  for (int i = 0; i < 64; ++i) ao[4 * i + dg] = sc[i] * inv;
}

// ---------------- out = attn @ x : LDS-free bf16 split MFMA ----------------
__global__ __launch_bounds__(256, 2) void k_out(const float* __restrict__ x,
                                                const float* __restrict__ attn,
                                                float* __restrict__ out) {
  int blk = blockIdx.x;            // 16*2*64 = 2048
  int tt = blk & 63;
  int ct = (blk >> 6) & 1;
  int b = blk >> 7;
  int t0 = tt << 7;
  int c0 = ct << 7;

  const float* ab = attn + (size_t)b * CC * CC;
  const float* xb = x + (size_t)b * CC * TT;

  int tid = threadIdx.x;
  int lane = tid & 63;
  int w = tid >> 6;
  int wm = (w >> 1) * 64, wn = (w & 1) * 64;
  int fr = lane & 15;
  int fkb = (lane >> 4) * 8;

  f32x4 acc[4][4];
  f32x4 z4 = {0.f, 0.f, 0.f, 0.f};
#pragma unroll
  for (int i = 0; i < 4; ++i)
#pragma unroll
    for (int j = 0; j < 4; ++j) acc[i][j] = z4;

  const float* ap[4];
  const float* bp[4];
#pragma unroll
  for (int m = 0; m < 4; ++m)
    ap[m] = ab + (size_t)(c0 + wm + m * 16 + fr) * CC + fkb;
#pragma unroll
  for (int n = 0; n < 4; ++n)
    bp[n] = xb + (size_t)fkb * TT + (t0 + wn + n * 16 + fr);

  for (int k = 0; k < CC; k += 32) {
    FragU aH[4], aL[4], bH[4], bL[4];
#pragma unroll
    for (int m = 0; m < 4; ++m) {
      float a8[8];
      *(f32x4*)&a8[0] = *(const f32x4*)(ap[m] + k);
      *(f32x4*)&a8[4] = *(const f32x4*)(ap[m] + k + 4);
      split8(a8, aH[m].u, aL[m].u);
    }
#pragma unroll
    for (int n = 0; n < 4; ++n) {
      float b8[8];
#pragma unroll
      for (int j = 0; j < 8; ++j)
        b8[j] = bp[n][(size_t)(k + j) * TT];
      split8(b8, bH[n].u, bL[n].u);
    }
#pragma unroll
    for (int mi = 0; mi < 4; ++mi)
#pragma unroll
      for (int ni = 0; ni < 4; ++ni) {
        acc[mi][ni] = __builtin_amdgcn_mfma_f32_16x16x32_bf16(aH[mi].s, bH[ni].s, acc[mi][ni], 0, 0, 0);
        acc[mi][ni] = __builtin_amdgcn_mfma_f32_16x16x32_bf16(aH[mi].s, bL[ni].s, acc[mi][ni], 0, 0, 0);
        acc[mi][ni] = __builtin_amdgcn_mfma_f32_16x16x32_bf16(aL[mi].s, bH[ni].s, acc[mi][ni], 0, 0, 0);
      }
  }

  int r4 = (lane >> 4) * 4;
#pragma unroll
  for (int mi = 0; mi < 4; ++mi) {
    int orow = c0 + wm + mi * 16 + r4;
#pragma unroll
    for (int ni = 0; ni < 4; ++ni) {
      int ocol = t0 + wn + ni * 16 + fr;
#pragma unroll
      for (int j = 0; j < 4; ++j)
        out[((size_t)b * CC + orow + j) * TT + ocol] = acc[mi][ni][j];
    }
  }
}

extern "C" void kernel_launch(void* const* d_in, const int* in_sizes, int n_in,
                              void* d_out, int out_size, void* d_ws, size_t ws_size,
                              hipStream_t stream) {
  (void)in_sizes; (void)n_in; (void)out_size; (void)ws_size;
  const float* x = (const float*)d_in[0];
  const float* qw = (const float*)d_in[1];
  const float* qb = (const float*)d_in[2];
  const float* kw = (const float*)d_in[3];
  const float* kb = (const float*)d_in[4];
  float* out = (float*)d_out;
  float* ws = (float*)d_ws;

  hipLaunchKernelGGL(k_stats, dim3(BB * 32), dim3(256), 0, stream, x, ws);
  hipLaunchKernelGGL(k_breduce, dim3(BB), dim3(256), 0, stream, ws);
  hipLaunchKernelGGL(k_gram, dim3(NSPLIT * 4 * BB), dim3(256), 0, stream, x, ws);
  hipLaunchKernelGGL(k_pccred, dim3(512), dim3(256), 0, stream, ws);
  hipLaunchKernelGGL(k_qk, dim3(BB * 4), dim3(256), 0, stream, qw, qb, kw, kb, ws);
  hipLaunchKernelGGL(k_attn, dim3(BB * 4), dim3(256), 0, stream, out, ws);
  hipLaunchKernelGGL(k_out, dim3(BB * 4 * 32), dim3(256), 0, stream,
                     x, out + (size_t)BB * CC * TT, out);
}

// Round 6
// 434.069 us; speedup vs baseline: 1.6023x; 1.0721x over previous
//
#include <hip/hip_runtime.h>
#include <math.h>

#define BB 16
#define CC 256
#define TT 8192
#define EE 32
#define NSPLIT 8

// workspace layout (float offsets)
#define OFF_M   0
#define OFF_VAR (OFF_M + BB*TT)
#define OFF_DEN (OFF_VAR + BB*TT)
#define OFF_Q   (OFF_DEN + 32)
#define OFF_K   (OFF_Q + BB*CC*EE)
#define OFF_GP  (OFF_K + BB*CC*EE)
#define OFF_PCC (OFF_GP + NSPLIT*BB*CC*CC)
// aH/aL (bf16 split of attn) alias the GP region: GP is dead after k_pccred,
// and k_attn (the writer) runs after k_pccred on the same stream.
#define OFF_AH  OFF_GP
#define OFF_AL  (OFF_GP + (BB*CC*CC/2))
// total ~9.97M floats (~39.9 MiB) of d_ws (same as round 5)

typedef __attribute__((ext_vector_type(8))) short bf16x8;
typedef __attribute__((ext_vector_type(4))) float f32x4;
typedef __attribute__((ext_vector_type(4))) unsigned int u32x4;

union FragU { u32x4 u; bf16x8 s; };

// pack the high 16 bits (truncated bf16) of two f32 into one u32: [f0hi | f1hi<<16]
__device__ __forceinline__ unsigned pack_hi2(float f0, float f1) {
  return __builtin_amdgcn_perm(__float_as_uint(f1), __float_as_uint(f0), 0x07060302u);
}

// split 8 f32 into hi (truncated bf16) and lo (bf16 of residual); hi+lo ~ 16-bit mantissa
__device__ __forceinline__ void split8(const float v[8], u32x4& hi, u32x4& lo) {
  float l[8];
#pragma unroll
  for (int i = 0; i < 8; ++i) {
    float h = __uint_as_float(__float_as_uint(v[i]) & 0xFFFF0000u);
    l[i] = v[i] - h;
  }
#pragma unroll
  for (int g = 0; g < 4; ++g) {
    hi[g] = pack_hi2(v[2 * g], v[2 * g + 1]);
    lo[g] = pack_hi2(l[2 * g], l[2 * g + 1]);
  }
}

// ---------------- stats: mean/var per (b,t), reduce over C ----------------
__global__ __launch_bounds__(256) void k_stats(const float* __restrict__ x,
                                               float* __restrict__ ws) {
  int bid = blockIdx.x;            // BB * (TT/256) = 512
  int b = bid >> 5;
  int t = ((bid & 31) << 8) | threadIdx.x;
  const float* xb = x + (size_t)b * CC * TT + t;
  float sum = 0.f, sq = 0.f;
#pragma unroll 4
  for (int c = 0; c < CC; ++c) {
    float v = xb[(size_t)c * TT];
    sum += v;
    sq = fmaf(v, v, sq);
  }
  float mean = sum * (1.0f / CC);
  float var = (sq - sum * mean) * (1.0f / (CC - 1));   // ddof=1
  ws[OFF_M + b * TT + t] = mean;
  ws[OFF_VAR + b * TT + t] = var;
}

// ---------------- denom[b] = sum_t var[b,t] ----------------
__global__ __launch_bounds__(256) void k_breduce(float* __restrict__ ws) {
  int b = blockIdx.x;              // BB
  const float* v = ws + OFF_VAR + (size_t)b * TT;
  float s = 0.f;
  for (int i = threadIdx.x; i < TT; i += 256) s += v[i];
#pragma unroll
  for (int off = 32; off; off >>= 1) s += __shfl_down(s, off, 64);
  __shared__ float red[4];
  int wid = threadIdx.x >> 6;
  if ((threadIdx.x & 63) == 0) red[wid] = s;
  __syncthreads();
  if (threadIdx.x == 0) ws[OFF_DEN + b] = red[0] + red[1] + red[2] + red[3];
}

// ---------------- centered Gram via bf16 hi/lo split MFMA ----------------
// GK=32 -> 32KB LDS -> 2 blocks/CU at 512 thr = 16 waves/CU (50% occ cap).
// Swizzle: 8-bf16 slot s' = s ^ ((row>>1)&3): 16 frag rows -> 8 bank-groups
// (2-way = free). Diagonal quadrants stage A only; B-frags read from A-LDS.
#define GK 32
__global__ __launch_bounds__(512, 4) void k_gram(const float* __restrict__ x,
                                                 float* __restrict__ ws) {
  __shared__ __align__(16) unsigned short AH[128 * GK];
  __shared__ __align__(16) unsigned short AL[128 * GK];
  __shared__ __align__(16) unsigned short BH[128 * GK];
  __shared__ __align__(16) unsigned short BL[128 * GK];

  int blk = blockIdx.x;            // NSPLIT*4*BB = 512
  int s = blk & 7;
  int tij = (blk >> 3) & 3;
  int b = blk >> 5;
  int ti = (tij >> 1) * 128, tj = (tij & 1) * 128;
  bool diag = (ti == tj);
  int k0 = s * (TT / NSPLIT);      // K window = 1024

  const float* xb = x + (size_t)b * CC * TT;
  const float* mb = ws + OFF_M + (size_t)b * TT + k0;

  int tid = threadIdx.x;
  int lane = tid & 63;
  int w = tid >> 6;                // 0..7
  int wm = (w & 1) * 64;           // 2 row slots of 64
  int wn = (w >> 1) * 32;          // 4 col slots of 32
  int fr = lane & 15;
  int g = lane >> 4;               // k-slot 0..3

  int sr = tid >> 2;               // staging row 0..127
  int ss = tid & 3;                // staging k-slot
  int wbase = sr * GK + ((ss ^ ((sr >> 1) & 3)) << 3);

  f32x4 acc[4][2];
  f32x4 z4 = {0.f, 0.f, 0.f, 0.f};
#pragma unroll
  for (int i = 0; i < 4; ++i) { acc[i][0] = z4; acc[i][1] = z4; }

  for (int kc = 0; kc < TT / NSPLIT; kc += GK) {
    const float* mr = mb + kc + ss * 8;
    const float* ar = xb + (size_t)(ti + sr) * TT + k0 + kc + ss * 8;
    {
      float m8[8], a8[8];
      *(f32x4*)&m8[0] = *(const f32x4*)(mr);
      *(f32x4*)&m8[4] = *(const f32x4*)(mr + 4);
      *(f32x4*)&a8[0] = *(const f32x4*)(ar);
      *(f32x4*)&a8[4] = *(const f32x4*)(ar + 4);
#pragma unroll
      for (int i = 0; i < 8; ++i) a8[i] -= m8[i];
      u32x4 hi, lo;
      split8(a8, hi, lo);
      *(u32x4*)&AH[wbase] = hi;
      *(u32x4*)&AL[wbase] = lo;
      if (!diag) {
        const float* br = xb + (size_t)(tj + sr) * TT + k0 + kc + ss * 8;
        float b8[8];
        *(f32x4*)&b8[0] = *(const f32x4*)(br);
        *(f32x4*)&b8[4] = *(const f32x4*)(br + 4);
#pragma unroll
        for (int i = 0; i < 8; ++i) b8[i] -= m8[i];
        split8(b8, hi, lo);
        *(u32x4*)&BH[wbase] = hi;
        *(u32x4*)&BL[wbase] = lo;
      }
    }
    __syncthreads();
    {
      const unsigned short* Bh = diag ? AH : BH;
      const unsigned short* Bl = diag ? AL : BL;
      FragU aH[4], aL[4], bH[2], bL[2];
#pragma unroll
      for (int m = 0; m < 4; ++m) {
        int r = wm + m * 16 + fr;
        int ad = r * GK + ((g ^ ((r >> 1) & 3)) << 3);
        aH[m].u = *(const u32x4*)&AH[ad];
        aL[m].u = *(const u32x4*)&AL[ad];
      }
#pragma unroll
      for (int n = 0; n < 2; ++n) {
        int r = wn + n * 16 + fr;
        int ad = r * GK + ((g ^ ((r >> 1) & 3)) << 3);
        bH[n].u = *(const u32x4*)&Bh[ad];
        bL[n].u = *(const u32x4*)&Bl[ad];
      }
#pragma unroll
      for (int mi = 0; mi < 4; ++mi)
#pragma unroll
        for (int ni = 0; ni < 2; ++ni) {
          acc[mi][ni] = __builtin_amdgcn_mfma_f32_16x16x32_bf16(aH[mi].s, bH[ni].s, acc[mi][ni], 0, 0, 0);
          acc[mi][ni] = __builtin_amdgcn_mfma_f32_16x16x32_bf16(aH[mi].s, bL[ni].s, acc[mi][ni], 0, 0, 0);
          acc[mi][ni] = __builtin_amdgcn_mfma_f32_16x16x32_bf16(aL[mi].s, bH[ni].s, acc[mi][ni], 0, 0, 0);
        }
    }
    __syncthreads();
  }

  float* gp = ws + OFF_GP + ((size_t)s * BB + b) * CC * CC;
  int r4 = g * 4;
#pragma unroll
  for (int mi = 0; mi < 4; ++mi) {
    int orow = ti + wm + mi * 16 + r4;
#pragma unroll
    for (int ni = 0; ni < 2; ++ni) {
      int ocol = tj + wn + ni * 16 + fr;
#pragma unroll
      for (int j = 0; j < 4; ++j)
        gp[(size_t)(orow + j) * CC + ocol] = acc[mi][ni][j];
    }
  }
}

// ---------------- pcc = (sum_s GP) / denom ----------------
__global__ __launch_bounds__(256) void k_pccred(float* __restrict__ ws) {
  size_t idx = ((size_t)blockIdx.x * 256 + threadIdx.x) * 8;  // grid 512
  int b = (int)(idx >> 16);
  float inv = 1.0f / ws[OFF_DEN + b];
  float4 s0 = make_float4(0.f, 0.f, 0.f, 0.f);
  float4 s1 = s0;
#pragma unroll
  for (int s = 0; s < NSPLIT; ++s) {
    const float* g = ws + OFF_GP + (size_t)s * BB * CC * CC + idx;
    float4 a = *(const float4*)g;
    float4 c = *(const float4*)(g + 4);
    s0.x += a.x; s0.y += a.y; s0.z += a.z; s0.w += a.w;
    s1.x += c.x; s1.y += c.y; s1.z += c.z; s1.w += c.w;
  }
  float* o = ws + OFF_PCC + idx;
  *(float4*)o = make_float4(s0.x * inv, s0.y * inv, s0.z * inv, s0.w * inv);
  *(float4*)(o + 4) = make_float4(s1.x * inv, s1.y * inv, s1.z * inv, s1.w * inv);
}

// ---------------- q,k = pcc @ W^T + b ----------------
__global__ __launch_bounds__(256) void k_qk(const float* __restrict__ qw,
                                            const float* __restrict__ qb,
                                            const float* __restrict__ kw,
                                            const float* __restrict__ kb,
                                            float* __restrict__ ws) {
  __shared__ float wq[CC][EE];
  __shared__ float wk[CC][EE];
  int blk = blockIdx.x;            // BB*4
  int b = blk >> 2;
  int c0 = (blk & 3) << 6;
  int tid = threadIdx.x;
  int e = tid & 31, d4 = tid >> 5;
#pragma unroll
  for (int p = 0; p < 8; ++p) {
    int dd = d4 * 4 + 32 * p;
    float4 qv = *(const float4*)(qw + (size_t)e * CC + dd);
    wq[dd + 0][e] = qv.x; wq[dd + 1][e] = qv.y; wq[dd + 2][e] = qv.z; wq[dd + 3][e] = qv.w;
    float4 kv = *(const float4*)(kw + (size_t)e * CC + dd);
    wk[dd + 0][e] = kv.x; wk[dd + 1][e] = kv.y; wk[dd + 2][e] = kv.z; wk[dd + 3][e] = kv.w;
  }
  __syncthreads();
  int r = tid >> 2;
  int eg = (tid & 3) << 3;
  float aq[8], ak[8];
#pragma unroll
  for (int j = 0; j < 8; ++j) { aq[j] = qb[eg + j]; ak[j] = kb[eg + j]; }
  const float* pr = ws + OFF_PCC + ((size_t)b * CC + c0 + r) * CC;
  for (int d = 0; d < CC; d += 4) {
    float4 p4 = *(const float4*)(pr + d);
    float pv[4] = {p4.x, p4.y, p4.z, p4.w};
#pragma unroll
    for (int u = 0; u < 4; ++u)
#pragma unroll
      for (int j = 0; j < 8; ++j) {
        aq[j] = fmaf(pv[u], wq[d + u][eg + j], aq[j]);
        ak[j] = fmaf(pv[u], wk[d + u][eg + j], ak[j]);
      }
  }
  float* qo = ws + OFF_Q + ((size_t)b * CC + c0 + r) * EE + eg;
  *(float4*)(qo + 0) = make_float4(aq[0], aq[1], aq[2], aq[3]);
  *(float4*)(qo + 4) = make_float4(aq[4], aq[5], aq[6], aq[7]);
  float* ko = ws + OFF_K + ((size_t)b * CC + c0 + r) * EE + eg;
  *(float4*)(ko + 0) = make_float4(ak[0], ak[1], ak[2], ak[3]);
  *(float4*)(ko + 4) = make_float4(ak[4], ak[5], ak[6], ak[7]);
}

// ------- scores + softmax -> attn (fp32 to d_out tail, bf16 hi/lo to ws) -------
// Each thread owns 64 CONTIGUOUS d (quad lane dg covers [dg*64, dg*64+64)),
// so the bf16 hi/lo pack is register-local and writes vectorize.
__global__ __launch_bounds__(256) void k_attn(float* __restrict__ out,
                                              float* __restrict__ ws) {
  __shared__ float kl[CC][36];
  int blk = blockIdx.x;            // BB*4
  int b = blk >> 2;
  int c0 = (blk & 3) << 6;
  int tid = threadIdx.x;
  const float* kv = ws + OFF_K + (size_t)b * CC * EE;
#pragma unroll
  for (int p = 0; p < 8; ++p) {
    int flat = (tid + 256 * p) * 4;
    int d = flat >> 5, e = flat & 31;
    *(float4*)&kl[d][e] = *(const float4*)(kv + flat);
  }
  __syncthreads();
  int r = tid >> 2, dg = tid & 3;
  const float* q = ws + OFF_Q + ((size_t)b * CC + c0 + r) * EE;
  float qv[EE];
#pragma unroll
  for (int j = 0; j < EE; j += 4) {
    float4 t4 = *(const float4*)(q + j);
    qv[j] = t4.x; qv[j + 1] = t4.y; qv[j + 2] = t4.z; qv[j + 3] = t4.w;
  }
  float sc[64];
  float mx = -1e30f;
#pragma unroll
  for (int i = 0; i < 64; ++i) {
    int d = dg * 64 + i;
    float s = 0.f;
#pragma unroll
    for (int u = 0; u < EE; u += 4) {
      float4 k4 = *(const float4*)&kl[d][u];
      s = fmaf(qv[u], k4.x, s);
      s = fmaf(qv[u + 1], k4.y, s);
      s = fmaf(qv[u + 2], k4.z, s);
      s = fmaf(qv[u + 3], k4.w, s);
    }
    s *= 0.0625f;                  // 1/sqrt(256)
    sc[i] = s;
    mx = fmaxf(mx, s);
  }
  mx = fmaxf(mx, __shfl_xor(mx, 1));
  mx = fmaxf(mx, __shfl_xor(mx, 2));
  float sum = 0.f;
#pragma unroll
  for (int i = 0; i < 64; ++i) { sc[i] = __expf(sc[i] - mx); sum += sc[i]; }
  sum += __shfl_xor(sum, 1);
  sum += __shfl_xor(sum, 2);
  float inv = 1.0f / sum;
  size_t rowoff = ((size_t)b * CC + c0 + r) * CC + dg * 64;
  float* ao = out + (size_t)BB * CC * TT + rowoff;
  unsigned short* aHp = (unsigned short*)(ws + OFF_AH) + rowoff;
  unsigned short* aLp = (unsigned short*)(ws + OFF_AL) + rowoff;
#pragma unroll
  for (int gi = 0; gi < 8; ++gi) {
    float v8[8];
#pragma unroll
    for (int j = 0; j < 8; ++j) v8[j] = sc[gi * 8 + j] * inv;
    *(float4*)(ao + gi * 8) = make_float4(v8[0], v8[1], v8[2], v8[3]);
    *(float4*)(ao + gi * 8 + 4) = make_float4(v8[4], v8[5], v8[6], v8[7]);
    u32x4 hi, lo;
    split8(v8, hi, lo);
    *(u32x4*)&aHp[gi * 8] = hi;
    *(u32x4*)&aLp[gi * 8] = lo;
  }
}

// ---------------- out = attn @ x : LDS-free bf16 split MFMA ----------------
// A operand (attn) comes pre-split from k_attn; B (x columns) split in-reg.
__global__ __launch_bounds__(256, 4) void k_out(const float* __restrict__ x,
                                                const float* __restrict__ ws_c,
                                                float* __restrict__ out) {
  int blk = blockIdx.x;            // 16*2*64 = 2048
  int tt = blk & 63;
  int ct = (blk >> 6) & 1;
  int b = blk >> 7;
  int t0 = tt << 7;
  int c0 = ct << 7;

  const float* xb = x + (size_t)b * CC * TT;
  const unsigned short* aHb = (const unsigned short*)(ws_c + OFF_AH);
  const unsigned short* aLb = (const unsigned short*)(ws_c + OFF_AL);

  int tid = threadIdx.x;
  int lane = tid & 63;
  int w = tid >> 6;
  int wm = (w >> 1) * 64, wn = (w & 1) * 64;
  int fr = lane & 15;
  int fkb = (lane >> 4) * 8;

  f32x4 acc[4][4];
  f32x4 z4 = {0.f, 0.f, 0.f, 0.f};
#pragma unroll
  for (int i = 0; i < 4; ++i)
#pragma unroll
    for (int j = 0; j < 4; ++j) acc[i][j] = z4;

  size_t arow[4];
  const float* bp[4];
#pragma unroll
  for (int m = 0; m < 4; ++m)
    arow[m] = ((size_t)b * CC + c0 + wm + m * 16 + fr) * CC + fkb;
#pragma unroll
  for (int n = 0; n < 4; ++n)
    bp[n] = xb + (size_t)fkb * TT + (t0 + wn + n * 16 + fr);

  for (int k = 0; k < CC; k += 32) {
    FragU aH[4], aL[4], bH[4], bL[4];
#pragma unroll
    for (int m = 0; m < 4; ++m) {
      aH[m].u = *(const u32x4*)&aHb[arow[m] + k];
      aL[m].u = *(const u32x4*)&aLb[arow[m] + k];
    }
#pragma unroll
    for (int n = 0; n < 4; ++n) {
      float b8[8];
#pragma unroll
      for (int j = 0; j < 8; ++j)
        b8[j] = bp[n][(size_t)(k + j) * TT];
      split8(b8, bH[n].u, bL[n].u);
    }
#pragma unroll
    for (int mi = 0; mi < 4; ++mi)
#pragma unroll
      for (int ni = 0; ni < 4; ++ni) {
        acc[mi][ni] = __builtin_amdgcn_mfma_f32_16x16x32_bf16(aH[mi].s, bH[ni].s, acc[mi][ni], 0, 0, 0);
        acc[mi][ni] = __builtin_amdgcn_mfma_f32_16x16x32_bf16(aH[mi].s, bL[ni].s, acc[mi][ni], 0, 0, 0);
        acc[mi][ni] = __builtin_amdgcn_mfma_f32_16x16x32_bf16(aL[mi].s, bH[ni].s, acc[mi][ni], 0, 0, 0);
      }
  }

  int r4 = (lane >> 4) * 4;
#pragma unroll
  for (int mi = 0; mi < 4; ++mi) {
    int orow = c0 + wm + mi * 16 + r4;
#pragma unroll
    for (int ni = 0; ni < 4; ++ni) {
      int ocol = t0 + wn + ni * 16 + fr;
#pragma unroll
      for (int j = 0; j < 4; ++j)
        out[((size_t)b * CC + orow + j) * TT + ocol] = acc[mi][ni][j];
    }
  }
}

extern "C" void kernel_launch(void* const* d_in, const int* in_sizes, int n_in,
                              void* d_out, int out_size, void* d_ws, size_t ws_size,
                              hipStream_t stream) {
  (void)in_sizes; (void)n_in; (void)out_size; (void)ws_size;
  const float* x = (const float*)d_in[0];
  const float* qw = (const float*)d_in[1];
  const float* qb = (const float*)d_in[2];
  const float* kw = (const float*)d_in[3];
  const float* kb = (const float*)d_in[4];
  float* out = (float*)d_out;
  float* ws = (float*)d_ws;

  hipLaunchKernelGGL(k_stats, dim3(BB * 32), dim3(256), 0, stream, x, ws);
  hipLaunchKernelGGL(k_breduce, dim3(BB), dim3(256), 0, stream, ws);
  hipLaunchKernelGGL(k_gram, dim3(NSPLIT * 4 * BB), dim3(512), 0, stream, x, ws);
  hipLaunchKernelGGL(k_pccred, dim3(512), dim3(256), 0, stream, ws);
  hipLaunchKernelGGL(k_qk, dim3(BB * 4), dim3(256), 0, stream, qw, qb, kw, kb, ws);
  hipLaunchKernelGGL(k_attn, dim3(BB * 4), dim3(256), 0, stream, out, ws);
  hipLaunchKernelGGL(k_out, dim3(BB * 4 * 32), dim3(256), 0, stream,
                     x, ws, out);
}